// Round 4
// baseline (2805.612 us; speedup 1.0000x reference)
//
#include <hip/hip_runtime.h>

#define BT   4      // batch tile per block
#define HID  64
#define G4   256    // 4*HID
#define SEQ  512
#define NOUT 12
#define NT   512    // threads per block: 256 gate rows x 2 k-halves

typedef float v16f __attribute__((ext_vector_type(16)));

__device__ __forceinline__ float sigf(float x)  { return 1.f / (1.f + __expf(-x)); }
__device__ __forceinline__ float tanhf_fast(float x) { return 1.f - 2.f / (1.f + __expf(2.f * x)); }

// Load this thread's 32-weight half-row (row g, cols [kb, kb+32)) into two v16f.
#define LOAD_HALF(M, Va, Vb)                                               \
    {                                                                      \
        const float4* p = (const float4*)&M[g * HID + kb];                 \
        _Pragma("unroll")                                                  \
        for (int j = 0; j < 4; ++j) {                                      \
            float4 q = p[j];                                               \
            Va[4*j+0] = q.x; Va[4*j+1] = q.y;                              \
            Va[4*j+2] = q.z; Va[4*j+3] = q.w;                              \
        }                                                                  \
        _Pragma("unroll")                                                  \
        for (int j = 0; j < 4; ++j) {                                      \
            float4 q = p[4 + j];                                           \
            Vb[4*j+0] = q.x; Vb[4*j+1] = q.y;                              \
            Vb[4*j+2] = q.z; Vb[4*j+3] = q.w;                              \
        }                                                                  \
    }

__global__ void __launch_bounds__(NT, 4) lstm2_fused(
    const float* __restrict__ x,      // [B, SEQ, 1]
    const float* __restrict__ w_ih0,  // [256, 1]
    const float* __restrict__ w_hh0,  // [256, 64]
    const float* __restrict__ b_ih0,  // [256]
    const float* __restrict__ b_hh0,  // [256]
    const float* __restrict__ w_ih1,  // [256, 64]
    const float* __restrict__ w_hh1,  // [256, 64]
    const float* __restrict__ b_ih1,  // [256]
    const float* __restrict__ b_hh1,  // [256]
    const float* __restrict__ fc_w,   // [12, 64]
    const float* __restrict__ fc_b,   // [12]
    float* __restrict__ out)          // [B, 12]
{
    __shared__ float xs[BT][SEQ];    // 8 KB
    __shared__ float h0s[BT][HID];   // 1 KB
    __shared__ float h1s[BT][HID];   // 1 KB
    __shared__ float gs[BT][G4];     // 4 KB

    const int tid  = threadIdx.x;
    const int g    = tid >> 1;        // gate row owned by this thread pair
    const int half = tid & 1;         // which 32-wide k-half
    const int kb   = half * 32;
    const int b0   = blockIdx.x * BT;

    // ---- loop-invariant half-rows as SSA vectors (6 x v16f = 96 VGPRs) ----
    v16f w0a = {}, w0b = {};   // w_hh0[g][kb..kb+32)
    v16f wia = {}, wib = {};   // w_ih1[g][kb..kb+32)
    v16f w1a = {}, w1b = {};   // w_hh1[g][kb..kb+32)
    LOAD_HALF(w_hh0, w0a, w0b);
    LOAD_HALF(w_ih1, wia, wib);
    LOAD_HALF(w_hh1, w1a, w1b);

    const float wih0g = w_ih0[g];                 // input size == 1
    const float bias0 = b_ih0[g] + b_hh0[g];
    const float bias1 = b_ih1[g] + b_hh1[g];

    // ---- stage this block's x tile into LDS ----
    for (int i = tid; i < BT * SEQ; i += NT) {
        int b = i >> 9, t = i & (SEQ - 1);
        xs[b][t] = x[(size_t)(b0 + b) * SEQ + t];
    }
    for (int i = tid; i < BT * HID; i += NT) {
        ((float*)h0s)[i] = 0.f;
        ((float*)h1s)[i] = 0.f;
    }
    // elementwise-phase identity (threads 0..255 only)
    const int eb = (tid >> 6) & 3;    // batch in tile
    const int ej = tid & 63;          // hidden unit
    float c0 = 0.f, c1 = 0.f;
    __syncthreads();

    for (int t = 0; t < SEQ; ++t) {
        float a[BT];
        // ===== layer 0: half dot-product over k in [kb, kb+32) =====
        // bias + x-term only contributed by half==0 (avoid double count after shfl sum)
#pragma unroll
        for (int b = 0; b < BT; ++b)
            a[b] = half ? 0.f : fmaf(xs[b][t], wih0g, bias0);
#pragma unroll
        for (int c = 0; c < 2; ++c) {
            v16f& W = c ? w0b : w0a;
#pragma unroll
            for (int i = 0; i < 16; i += 4) {
#pragma unroll
                for (int b = 0; b < BT; ++b) {
                    float4 hv = *(const float4*)&h0s[b][kb + c * 16 + i];
                    a[b] = fmaf(hv.x, W[i + 0], a[b]);
                    a[b] = fmaf(hv.y, W[i + 1], a[b]);
                    a[b] = fmaf(hv.z, W[i + 2], a[b]);
                    a[b] = fmaf(hv.w, W[i + 3], a[b]);
                }
            }
        }
#pragma unroll
        for (int b = 0; b < BT; ++b) a[b] += __shfl_xor(a[b], 1);
        // half 0 writes b=0,1; half 1 writes b=2,3 (2-way bank alias = free)
        gs[half ? 2 : 0][g] = half ? a[2] : a[0];
        gs[half ? 3 : 1][g] = half ? a[3] : a[1];
        __syncthreads();

        // ===== elementwise 0 (threads 0..255; c0 in registers) =====
        if (tid < BT * HID) {
            float ig = sigf(gs[eb][ej]);
            float fg = sigf(gs[eb][64 + ej]);
            float gg = tanhf_fast(gs[eb][128 + ej]);
            float og = sigf(gs[eb][192 + ej]);
            c0 = fg * c0 + ig * gg;
            h0s[eb][ej] = og * tanhf_fast(c0);
        }
        __syncthreads();

        // ===== layer 1: half dot-products vs h0_new (w_ih1) and h1_old (w_hh1) =====
#pragma unroll
        for (int b = 0; b < BT; ++b) a[b] = half ? 0.f : bias1;
#pragma unroll
        for (int c = 0; c < 2; ++c) {
            v16f& Wi = c ? wib : wia;
            v16f& W1 = c ? w1b : w1a;
#pragma unroll
            for (int i = 0; i < 16; i += 4) {
#pragma unroll
                for (int b = 0; b < BT; ++b) {
                    float4 hv  = *(const float4*)&h0s[b][kb + c * 16 + i];
                    float4 h1v = *(const float4*)&h1s[b][kb + c * 16 + i];
                    a[b] = fmaf(hv.x,  Wi[i + 0], a[b]);
                    a[b] = fmaf(hv.y,  Wi[i + 1], a[b]);
                    a[b] = fmaf(hv.z,  Wi[i + 2], a[b]);
                    a[b] = fmaf(hv.w,  Wi[i + 3], a[b]);
                    a[b] = fmaf(h1v.x, W1[i + 0], a[b]);
                    a[b] = fmaf(h1v.y, W1[i + 1], a[b]);
                    a[b] = fmaf(h1v.z, W1[i + 2], a[b]);
                    a[b] = fmaf(h1v.w, W1[i + 3], a[b]);
                }
            }
        }
#pragma unroll
        for (int b = 0; b < BT; ++b) a[b] += __shfl_xor(a[b], 1);
        gs[half ? 2 : 0][g] = half ? a[2] : a[0];
        gs[half ? 3 : 1][g] = half ? a[3] : a[1];
        __syncthreads();

        // ===== elementwise 1 =====
        if (tid < BT * HID) {
            float ig = sigf(gs[eb][ej]);
            float fg = sigf(gs[eb][64 + ej]);
            float gg = tanhf_fast(gs[eb][128 + ej]);
            float og = sigf(gs[eb][192 + ej]);
            c1 = fg * c1 + ig * gg;
            h1s[eb][ej] = og * tanhf_fast(c1);
        }
        __syncthreads();
    }

    // ===== final projection: out[b][o] = fc_b[o] + h1 . fc_w[o] =====
    if (tid < BT * NOUT) {
        int b = tid / NOUT, o = tid % NOUT;
        float acc = fc_b[o];
#pragma unroll
        for (int j = 0; j < HID; ++j)
            acc = fmaf(fc_w[o * HID + j], h1s[b][j], acc);
        out[(size_t)(b0 + b) * NOUT + o] = acc;
    }
}

extern "C" void kernel_launch(void* const* d_in, const int* in_sizes, int n_in,
                              void* d_out, int out_size, void* d_ws, size_t ws_size,
                              hipStream_t stream) {
    const float* x     = (const float*)d_in[0];
    const float* w_ih0 = (const float*)d_in[1];
    const float* w_hh0 = (const float*)d_in[2];
    const float* b_ih0 = (const float*)d_in[3];
    const float* b_hh0 = (const float*)d_in[4];
    const float* w_ih1 = (const float*)d_in[5];
    const float* w_hh1 = (const float*)d_in[6];
    const float* b_ih1 = (const float*)d_in[7];
    const float* b_hh1 = (const float*)d_in[8];
    const float* fc_w  = (const float*)d_in[9];
    const float* fc_b  = (const float*)d_in[10];

    const int B = in_sizes[0] / SEQ;          // 2048
    dim3 grid(B / BT);                        // 512 blocks x 512 thr = full device at 4 waves/EU
    lstm2_fused<<<grid, NT, 0, stream>>>(x, w_ih0, w_hh0, b_ih0, b_hh0,
                                         w_ih1, w_hh1, b_ih1, b_hh1,
                                         fc_w, fc_b, (float*)d_out);
}